// Round 2
// 417.746 us; speedup vs baseline: 1.0285x; 1.0285x over previous
//
#include <hip/hip_runtime.h>

// Haar IDWT2: inputs LL,LH,HL,HH each [B=16, C=64, H2=128, W2=128] fp32.
// Output [16, 64, 256, 256] fp32.
//
// Mapping (both sides hole-free):
//   lane k of a wave owns input cols (2k, 2k+1) of one input row  -> dwordx2 loads,
//   and stores 16B (output cols 4k..4k+3) to output rows 2i, 2i+1 -> dwordx4
//   stores; each store instruction covers one full 1024-B output row.
//
// Round 2 = Round 1 with the compile fix:
//   __builtin_nontemporal_* requires NATIVE vector types, not HIP_vector_type.
//   Use clang ext_vector_type typedefs (bit-identical layout).

#define H2 128
#define W2 128

typedef float nf2 __attribute__((ext_vector_type(2)));
typedef float nf4 __attribute__((ext_vector_type(4)));

__global__ __launch_bounds__(256) void idwt_kernel(
    const nf2* __restrict__ LL, const nf2* __restrict__ LH,
    const nf2* __restrict__ HL, const nf2* __restrict__ HH,
    nf4* __restrict__ out, int half) {
  int t0 = blockIdx.x * blockDim.x + threadIdx.x;
  if (t0 >= half) return;
  int t1 = t0 + half;  // second unit, 128 MiB away in each input stream

  // Issue all 8 loads up front (independent -> 8 outstanding dwordx2).
  nf2 ll0 = __builtin_nontemporal_load(&LL[t0]);
  nf2 lh0 = __builtin_nontemporal_load(&LH[t0]);
  nf2 hl0 = __builtin_nontemporal_load(&HL[t0]);
  nf2 hh0 = __builtin_nontemporal_load(&HH[t0]);
  nf2 ll1 = __builtin_nontemporal_load(&LL[t1]);
  nf2 lh1 = __builtin_nontemporal_load(&LH[t1]);
  nf2 hl1 = __builtin_nontemporal_load(&HL[t1]);
  nf2 hh1 = __builtin_nontemporal_load(&HH[t1]);

  nf4 r0, r1, r2, r3;
  // unit 0, col 2k
  {
    float s1 = ll0.x + lh0.x, s2 = hl0.x + hh0.x;
    float d1 = ll0.x - lh0.x, d2 = hl0.x - hh0.x;
    r0.x = (s1 + s2) * 0.5f;  // a: out[2i, 4k]
    r0.y = (s1 - s2) * 0.5f;  // b: out[2i, 4k+1]
    r1.x = (d1 + d2) * 0.5f;  // c: out[2i+1, 4k]
    r1.y = (d1 - d2) * 0.5f;  // d: out[2i+1, 4k+1]
  }
  // unit 0, col 2k+1
  {
    float s1 = ll0.y + lh0.y, s2 = hl0.y + hh0.y;
    float d1 = ll0.y - lh0.y, d2 = hl0.y - hh0.y;
    r0.z = (s1 + s2) * 0.5f;
    r0.w = (s1 - s2) * 0.5f;
    r1.z = (d1 + d2) * 0.5f;
    r1.w = (d1 - d2) * 0.5f;
  }
  // unit 1, col 2k
  {
    float s1 = ll1.x + lh1.x, s2 = hl1.x + hh1.x;
    float d1 = ll1.x - lh1.x, d2 = hl1.x - hh1.x;
    r2.x = (s1 + s2) * 0.5f;
    r2.y = (s1 - s2) * 0.5f;
    r3.x = (d1 + d2) * 0.5f;
    r3.y = (d1 - d2) * 0.5f;
  }
  // unit 1, col 2k+1
  {
    float s1 = ll1.y + lh1.y, s2 = hl1.y + hh1.y;
    float d1 = ll1.y - lh1.y, d2 = hl1.y - hh1.y;
    r2.z = (s1 + s2) * 0.5f;
    r2.w = (s1 - s2) * 0.5f;
    r3.z = (d1 + d2) * 0.5f;
    r3.w = (d1 - d2) * 0.5f;
  }

  // output quad index: plane*(256 rows * 64 quads) + (2i)*64 + j2
  int j2_0 = t0 & 63;
  int i0 = (t0 >> 6) & (H2 - 1);
  int p0 = t0 >> 13;
  int oq0 = (p0 << 14) | (i0 << 7) | j2_0;

  int j2_1 = t1 & 63;
  int i1 = (t1 >> 6) & (H2 - 1);
  int p1 = t1 >> 13;
  int oq1 = (p1 << 14) | (i1 << 7) | j2_1;

  __builtin_nontemporal_store(r0, &out[oq0]);       // row 2*i0
  __builtin_nontemporal_store(r1, &out[oq0 + 64]);  // row 2*i0+1
  __builtin_nontemporal_store(r2, &out[oq1]);       // row 2*i1
  __builtin_nontemporal_store(r3, &out[oq1 + 64]);  // row 2*i1+1
}

extern "C" void kernel_launch(void* const* d_in, const int* in_sizes, int n_in,
                              void* d_out, int out_size, void* d_ws, size_t ws_size,
                              hipStream_t stream) {
  const nf2* LL = (const nf2*)d_in[0];
  const nf2* LH = (const nf2*)d_in[1];
  const nf2* HL = (const nf2*)d_in[2];
  const nf2* HH = (const nf2*)d_in[3];
  nf4* out = (nf4*)d_out;

  int npairs = in_sizes[0] / 2;  // 16*64*128*128/2 = 8,388,608
  int half = npairs / 2;         // 4,194,304 units of 2 input cols each
  int block = 256;
  int grid = (half + block - 1) / block;  // 16384 blocks
  idwt_kernel<<<grid, block, 0, stream>>>(LL, LH, HL, HH, out, half);
}